// Round 1
// baseline (143.999 us; speedup 1.0000x reference)
//
#include <hip/hip_runtime.h>
#include <stdint.h>

typedef short bf16x8 __attribute__((ext_vector_type(8)));
typedef float f32x4 __attribute__((ext_vector_type(4)));

#define SEQ_ 2048
#define DM_ 768
#define NH_ 12

__device__ __forceinline__ unsigned short f2bf(float f) {
  unsigned int u = __float_as_uint(f);
  u += 0x7fffu + ((u >> 16) & 1u);
  return (unsigned short)(u >> 16);
}

__device__ __forceinline__ void load_lds16(const unsigned short* g, unsigned short* l) {
  __builtin_amdgcn_global_load_lds((__attribute__((address_space(1))) void*)g,
                                   (__attribute__((address_space(3))) void*)l, 16, 0, 0);
}

// ---------------- x (fp32) -> bf16 ----------------
__global__ __launch_bounds__(256) void cvt_bf16(const float* __restrict__ s,
                                                unsigned short* __restrict__ d, int n) {
  int i = (blockIdx.x * 256 + threadIdx.x) * 4;
  if (i >= n) return;
  float4 v = *(const float4*)(s + i);
  unsigned short o[4] = {f2bf(v.x), f2bf(v.y), f2bf(v.z), f2bf(v.w)};
  *(uint2*)(d + i) = *(const uint2*)o;
}

// ---------------- fp32 [R][C] -> bf16 [C][R] ----------------
__global__ __launch_bounds__(256) void transpose_bf(const float* __restrict__ src,
                                                    unsigned short* __restrict__ dst,
                                                    int R, int C) {
  __shared__ float t[64][65];
  int c0 = blockIdx.x << 6, r0 = blockIdx.y << 6;
  int tid = threadIdx.x;
#pragma unroll
  for (int i = 0; i < 4; i++) {
    int e = (i * 256 + tid) * 4;
    int r = e >> 6, c = e & 63;
    float4 v = *(const float4*)(src + (size_t)(r0 + r) * C + c0 + c);
    t[r][c] = v.x; t[r][c + 1] = v.y; t[r][c + 2] = v.z; t[r][c + 3] = v.w;
  }
  __syncthreads();
#pragma unroll
  for (int i = 0; i < 4; i++) {
    int e = (i * 256 + tid) * 4;
    int r = e >> 6, c = e & 63;
    unsigned short o4[4];
#pragma unroll
    for (int j = 0; j < 4; j++) o4[j] = f2bf(t[c + j][r]);
    *(uint2*)(dst + (size_t)(c0 + r) * R + r0 + c) = *(const uint2*)o4;
  }
}

// ---------------- V [BH][S][64] bf16 -> Vt [BH][64][S] bf16 ----------------
__global__ __launch_bounds__(256) void transpose_v(const unsigned short* __restrict__ V,
                                                   unsigned short* __restrict__ Vt) {
  __shared__ unsigned short t[64][72];
  int blk = blockIdx.x;
  int bh = blk >> 5, s0 = (blk & 31) << 6;
  int tid = threadIdx.x;
#pragma unroll
  for (int i = 0; i < 2; i++) {
    int e = (i * 256 + tid) * 8;
    int r = e >> 6, c = e & 63;
    *(uint4*)&t[r][c] = *(const uint4*)(V + ((size_t)(bh << 11) + s0 + r) * 64 + c);
  }
  __syncthreads();
#pragma unroll
  for (int i = 0; i < 2; i++) {
    int e = (i * 256 + tid) * 8;
    int hd = e >> 6, c = e & 63;
    unsigned short v[8];
#pragma unroll
    for (int j = 0; j < 8; j++) v[j] = t[c + j][hd];
    *(uint4*)(Vt + ((size_t)(bh << 6) + hd) * SEQ_ + s0 + c) = *(const uint4*)v;
  }
}

// ---------------- GEMM mainloop: C[128x128] += A[m0..][K=768] * Bt[n0..][K=768]^T ----------------
__device__ __forceinline__ void gemm_mainloop(const unsigned short* __restrict__ A,
                                              const unsigned short* __restrict__ Bt,
                                              int m0, int n0,
                                              unsigned short* As, unsigned short* Bs,
                                              f32x4 acc[4][4]) {
  const int K = 768;
  int tid = threadIdx.x, wv = tid >> 6, ln = tid & 63, quad = ln >> 4, lrow = ln & 15;
  const unsigned short* a0 = A + (size_t)(m0 + (tid >> 2)) * K + (tid & 3) * 8;
  const unsigned short* a1 = a0 + (size_t)64 * K;
  const unsigned short* b0 = Bt + (size_t)(n0 + (tid >> 2)) * K + (tid & 3) * 8;
  const unsigned short* b1 = b0 + (size_t)64 * K;
  int mw = (wv >> 1) << 6, nw = (wv & 1) << 6;
  for (int kt = 0; kt < K; kt += 32) {
    load_lds16(a0 + kt, As + tid * 8);
    load_lds16(a1 + kt, As + (256 + tid) * 8);
    load_lds16(b0 + kt, Bs + tid * 8);
    load_lds16(b1 + kt, Bs + (256 + tid) * 8);
    __syncthreads();
    bf16x8 af[4], bfr[4];
#pragma unroll
    for (int i = 0; i < 4; i++)
      af[i] = *(const bf16x8*)(As + (mw + i * 16 + lrow) * 32 + quad * 8);
#pragma unroll
    for (int j = 0; j < 4; j++)
      bfr[j] = *(const bf16x8*)(Bs + (nw + j * 16 + lrow) * 32 + quad * 8);
#pragma unroll
    for (int i = 0; i < 4; i++)
#pragma unroll
      for (int j = 0; j < 4; j++)
        acc[i][j] = __builtin_amdgcn_mfma_f32_16x16x32_bf16(af[i], bfr[j], acc[i][j], 0, 0, 0);
    __syncthreads();
  }
}

// ---------------- GEMM1: qkv with scatter epilogue into Q/K/V [B][H][S][64] bf16 ----------------
__global__ __launch_bounds__(256, 2) void gemm_qkv(const unsigned short* __restrict__ A,
                                                   const unsigned short* __restrict__ Bt,
                                                   unsigned short* __restrict__ Qb,
                                                   unsigned short* __restrict__ Kb,
                                                   unsigned short* __restrict__ Vb) {
  __shared__ unsigned short As[128 * 32];
  __shared__ unsigned short Bs[128 * 32];
  f32x4 acc[4][4];
  f32x4 z = {0.f, 0.f, 0.f, 0.f};
#pragma unroll
  for (int i = 0; i < 4; i++)
#pragma unroll
    for (int j = 0; j < 4; j++) acc[i][j] = z;
  int m0 = blockIdx.x << 7, n0 = blockIdx.y << 7;
  gemm_mainloop(A, Bt, m0, n0, As, Bs, acc);
  int tid = threadIdx.x, wv = tid >> 6, ln = tid & 63, quad = ln >> 4, lrow = ln & 15;
  int mw = m0 + ((wv >> 1) << 6), nw = n0 + ((wv & 1) << 6);
  int bb = m0 >> 11;  // batch, constant per block (2048 % 128 == 0)
#pragma unroll
  for (int j = 0; j < 4; j++) {
    int nbase = nw + j * 16;
    int which = nbase / DM_, rem = nbase % DM_;
    int h = rem >> 6, hdb = (rem & 63) + lrow;
    unsigned short* dstp = which == 0 ? Qb : (which == 1 ? Kb : Vb);
    size_t hoff = (size_t)(bb * NH_ + h) << 11;
#pragma unroll
    for (int i = 0; i < 4; i++) {
#pragma unroll
      for (int r = 0; r < 4; r++) {
        int m = mw + i * 16 + quad * 4 + r;
        int s = m & (SEQ_ - 1);
        dstp[((hoff + s) << 6) + hdb] = f2bf(acc[i][j][r]);
      }
    }
  }
}

// ---------------- GEMM2: out(fp32) = attn_bf @ Wo_t^T ----------------
__global__ __launch_bounds__(256, 2) void gemm_out(const unsigned short* __restrict__ A,
                                                   const unsigned short* __restrict__ Bt,
                                                   float* __restrict__ out) {
  __shared__ unsigned short As[128 * 32];
  __shared__ unsigned short Bs[128 * 32];
  f32x4 acc[4][4];
  f32x4 z = {0.f, 0.f, 0.f, 0.f};
#pragma unroll
  for (int i = 0; i < 4; i++)
#pragma unroll
    for (int j = 0; j < 4; j++) acc[i][j] = z;
  int m0 = blockIdx.x << 7, n0 = blockIdx.y << 7;
  gemm_mainloop(A, Bt, m0, n0, As, Bs, acc);
  int tid = threadIdx.x, wv = tid >> 6, ln = tid & 63, quad = ln >> 4, lrow = ln & 15;
  int mw = m0 + ((wv >> 1) << 6), nw = n0 + ((wv & 1) << 6);
#pragma unroll
  for (int i = 0; i < 4; i++)
#pragma unroll
    for (int j = 0; j < 4; j++)
#pragma unroll
      for (int r = 0; r < 4; r++)
        out[(size_t)(mw + i * 16 + quad * 4 + r) * DM_ + nw + j * 16 + lrow] = acc[i][j][r];
}

// ---------------- windowed attention ----------------
// grid: BH*32 blocks; block = 4 waves; wave w handles 16 queries at q0+16w.
// Wave key window (local to kstart=q0-64): [16w, 16w+143]; P padded to 160 keys.
__global__ __launch_bounds__(256, 2) void attn_kernel(const unsigned short* __restrict__ Qb,
                                                      const unsigned short* __restrict__ Kb,
                                                      const unsigned short* __restrict__ Vtb,
                                                      const float* __restrict__ pmask,
                                                      unsigned short* __restrict__ Obf) {
  __shared__ unsigned short Ps[4][16 * 168];  // per-wave P, padded stride 168
  int blk = blockIdx.x;
  int tile = blk & 31, bh = blk >> 5;
  int b = bh / NH_, h = bh % NH_;
  int q0 = tile << 6;
  int kstart = q0 - 64;
  int tid = threadIdx.x, wv = tid >> 6, ln = tid & 63, quad = ln >> 4, lrow = ln & 15;
  int kb = wv << 4;
  int qw = q0 + (wv << 4);

  const unsigned short* Qg = Qb + ((size_t)bh << 11) * 64;
  const unsigned short* Kg = Kb + ((size_t)bh << 11) * 64;
  const unsigned short* Vg = Vtb + ((size_t)bh << 6) * SEQ_;

  bf16x8 qf0 = *(const bf16x8*)(Qg + (qw + lrow) * 64 + quad * 8);
  bf16x8 qf1 = *(const bf16x8*)(Qg + (qw + lrow) * 64 + 32 + quad * 8);

  float sc[9][4];
#pragma unroll
  for (int t = 0; t < 9; t++) {
    int kg = kstart + kb + t * 16 + lrow;
    int kgc = kg < 0 ? 0 : (kg > SEQ_ - 1 ? SEQ_ - 1 : kg);
    bf16x8 kf0 = *(const bf16x8*)(Kg + (size_t)kgc * 64 + quad * 8);
    bf16x8 kf1 = *(const bf16x8*)(Kg + (size_t)kgc * 64 + 32 + quad * 8);
    f32x4 c = {0.f, 0.f, 0.f, 0.f};
    c = __builtin_amdgcn_mfma_f32_16x16x32_bf16(qf0, kf0, c, 0, 0, 0);
    c = __builtin_amdgcn_mfma_f32_16x16x32_bf16(qf1, kf1, c, 0, 0, 0);
    float mneg = -1e30f;
    if (kg >= 0 && kg < SEQ_) {
      if (pmask[(b << 11) + kg] != 0.0f) mneg = 0.0f;
    }
#pragma unroll
    for (int r = 0; r < 4; r++) {
      int qg = qw + quad * 4 + r;
      int d = qg - kg;
      float wneg = (d >= -64 && d <= 64) ? 0.0f : -1e30f;
      sc[t][r] = c[r] * 0.125f + mneg + wneg;
    }
  }
  // full softmax per row (rows live across the 16 lanes of each quad)
  float inv[4];
#pragma unroll
  for (int r = 0; r < 4; r++) {
    float mx = sc[0][r];
#pragma unroll
    for (int t = 1; t < 9; t++) mx = fmaxf(mx, sc[t][r]);
    mx = fmaxf(mx, __shfl_xor(mx, 1));
    mx = fmaxf(mx, __shfl_xor(mx, 2));
    mx = fmaxf(mx, __shfl_xor(mx, 4));
    mx = fmaxf(mx, __shfl_xor(mx, 8));
    float s = 0.f;
#pragma unroll
    for (int t = 0; t < 9; t++) {
      sc[t][r] = __expf(sc[t][r] - mx);
      s += sc[t][r];
    }
    s += __shfl_xor(s, 1);
    s += __shfl_xor(s, 2);
    s += __shfl_xor(s, 4);
    s += __shfl_xor(s, 8);
    inv[r] = 1.0f / s;
  }
  // write P (C-layout -> LDS rows), zero the 144..159 pad
  unsigned short* Pw = &Ps[wv][0];
#pragma unroll
  for (int t = 0; t < 9; t++)
#pragma unroll
    for (int r = 0; r < 4; r++)
      Pw[(quad * 4 + r) * 168 + t * 16 + lrow] = f2bf(sc[t][r] * inv[r]);
  {
    int row = ln >> 2, c0 = 144 + (ln & 3) * 4;
    uint2 zz; zz.x = 0; zz.y = 0;
    *(uint2*)(Pw + row * 168 + c0) = zz;
  }
  __syncthreads();
  // PV: A = P[q][key], B = Vt[hd][key]
  f32x4 o[4];
  f32x4 z = {0.f, 0.f, 0.f, 0.f};
#pragma unroll
  for (int tt = 0; tt < 4; tt++) o[tt] = z;
#pragma unroll
  for (int ks = 0; ks < 5; ks++) {
    bf16x8 pf = *(const bf16x8*)(Pw + lrow * 168 + ks * 32 + quad * 8);
    int kg = kstart + kb + ks * 32 + quad * 8;
    int kgc = kg < 0 ? 0 : (kg > SEQ_ - 8 ? SEQ_ - 8 : kg);
#pragma unroll
    for (int tt = 0; tt < 4; tt++) {
      bf16x8 vf = *(const bf16x8*)(Vg + (size_t)(tt * 16 + lrow) * SEQ_ + kgc);
      o[tt] = __builtin_amdgcn_mfma_f32_16x16x32_bf16(pf, vf, o[tt], 0, 0, 0);
    }
  }
  // write O -> attn_bf [B*S][768]
#pragma unroll
  for (int tt = 0; tt < 4; tt++)
#pragma unroll
    for (int r = 0; r < 4; r++) {
      int s_ = qw + quad * 4 + r;
      Obf[((size_t)(b << 11) + s_) * DM_ + h * 64 + tt * 16 + lrow] = f2bf(o[tt][r]);
    }
}

extern "C" void kernel_launch(void* const* d_in, const int* in_sizes, int n_in,
                              void* d_out, int out_size, void* d_ws, size_t ws_size,
                              hipStream_t stream) {
  const float* x = (const float*)d_in[0];
  const float* pmask = (const float*)d_in[1];
  const float* Wqkv = (const float*)d_in[2];
  const float* Wo = (const float*)d_in[3];
  float* out = (float*)d_out;
  char* ws = (char*)d_ws;

  // workspace layout (bytes)
  unsigned short* xb    = (unsigned short*)(ws + 0);         // 4096*768*2   = 6291456
  unsigned short* wqkvt = (unsigned short*)(ws + 6291456);   // 2304*768*2   = 3538944
  unsigned short* wot   = (unsigned short*)(ws + 9830400);   // 768*768*2    = 1179648
  unsigned short* Qb    = (unsigned short*)(ws + 11010048);  // 24*2048*64*2 = 6291456
  unsigned short* Kb    = (unsigned short*)(ws + 17301504);
  unsigned short* Vb    = (unsigned short*)(ws + 23592960);
  unsigned short* Vtb   = (unsigned short*)(ws + 29884416);  // end 36175872
  unsigned short* attn_bf = xb;  // xb dead after gemm_qkv; reuse

  cvt_bf16<<<3072, 256, 0, stream>>>(x, xb, 4096 * DM_);
  transpose_bf<<<dim3(36, 12), 256, 0, stream>>>(Wqkv, wqkvt, DM_, 3 * DM_);
  transpose_bf<<<dim3(12, 12), 256, 0, stream>>>(Wo, wot, DM_, DM_);
  gemm_qkv<<<dim3(32, 18), 256, 0, stream>>>(xb, wqkvt, Qb, Kb, Vb);
  transpose_v<<<768, 256, 0, stream>>>(Vb, Vtb);
  attn_kernel<<<768, 256, 0, stream>>>(Qb, Kb, Vtb, pmask, attn_bf);
  gemm_out<<<dim3(32, 6), 256, 0, stream>>>(attn_bf, wot, out);
}

// Round 2
// 134.585 us; speedup vs baseline: 1.0700x; 1.0700x over previous
//
#include <hip/hip_runtime.h>
#include <stdint.h>

typedef short bf16x8 __attribute__((ext_vector_type(8)));
typedef float f32x4 __attribute__((ext_vector_type(4)));

#define SEQ_ 2048
#define DM_ 768
#define NH_ 12

__device__ __forceinline__ unsigned short f2bf(float f) {
  unsigned int u = __float_as_uint(f);
  u += 0x7fffu + ((u >> 16) & 1u);
  return (unsigned short)(u >> 16);
}

__device__ __forceinline__ void load_lds16(const unsigned short* g, unsigned short* l) {
  __builtin_amdgcn_global_load_lds((__attribute__((address_space(1))) void*)g,
                                   (__attribute__((address_space(3))) void*)l, 16, 0, 0);
}

// ---------------- prep: x->bf16 cast + Wqkv/Wo transpose+cast, one kernel ----------------
__device__ __forceinline__ void transpose_body(const float* __restrict__ src,
                                               unsigned short* __restrict__ dst,
                                               int R, int C, int bx, int by,
                                               float (*t)[65]) {
  int c0 = bx << 6, r0 = by << 6;
  int tid = threadIdx.x;
#pragma unroll
  for (int i = 0; i < 4; i++) {
    int e = (i * 256 + tid) * 4;
    int r = e >> 6, c = e & 63;
    float4 v = *(const float4*)(src + (size_t)(r0 + r) * C + c0 + c);
    t[r][c] = v.x; t[r][c + 1] = v.y; t[r][c + 2] = v.z; t[r][c + 3] = v.w;
  }
  __syncthreads();
#pragma unroll
  for (int i = 0; i < 4; i++) {
    int e = (i * 256 + tid) * 4;
    int r = e >> 6, c = e & 63;
    unsigned short o4[4];
#pragma unroll
    for (int j = 0; j < 4; j++) o4[j] = f2bf(t[c + j][r]);
    *(uint2*)(dst + (size_t)(c0 + r) * R + r0 + c) = *(const uint2*)o4;
  }
}

__global__ __launch_bounds__(256) void prep(const float* __restrict__ x,
                                            const float* __restrict__ Wqkv,
                                            const float* __restrict__ Wo,
                                            unsigned short* __restrict__ xb,
                                            unsigned short* __restrict__ wqkvt,
                                            unsigned short* __restrict__ wot) {
  __shared__ float t[64][65];
  int blk = blockIdx.x;
  if (blk < 3072) {
    int i = (blk * 256 + threadIdx.x) * 4;
    float4 v = *(const float4*)(x + i);
    unsigned short o[4] = {f2bf(v.x), f2bf(v.y), f2bf(v.z), f2bf(v.w)};
    *(uint2*)(xb + i) = *(const uint2*)o;
  } else if (blk < 3072 + 432) {
    int idx = blk - 3072;
    transpose_body(Wqkv, wqkvt, DM_, 3 * DM_, idx % 36, idx / 36, t);
  } else {
    int idx = blk - 3504;
    transpose_body(Wo, wot, DM_, DM_, idx % 12, idx / 12, t);
  }
}

// ---------------- GEMM mainloop: C[128x128] += A[m0..][K=768] * Bt[n0..][K=768]^T ----------------
__device__ __forceinline__ void gemm_mainloop(const unsigned short* __restrict__ A,
                                              const unsigned short* __restrict__ Bt,
                                              int m0, int n0,
                                              unsigned short* As, unsigned short* Bs,
                                              f32x4 acc[4][4]) {
  const int K = 768;
  int tid = threadIdx.x, wv = tid >> 6, ln = tid & 63, quad = ln >> 4, lrow = ln & 15;
  const unsigned short* a0 = A + (size_t)(m0 + (tid >> 2)) * K + (tid & 3) * 8;
  const unsigned short* a1 = a0 + (size_t)64 * K;
  const unsigned short* b0 = Bt + (size_t)(n0 + (tid >> 2)) * K + (tid & 3) * 8;
  const unsigned short* b1 = b0 + (size_t)64 * K;
  int mw = (wv >> 1) << 6, nw = (wv & 1) << 6;
  for (int kt = 0; kt < K; kt += 32) {
    load_lds16(a0 + kt, As + tid * 8);
    load_lds16(a1 + kt, As + (256 + tid) * 8);
    load_lds16(b0 + kt, Bs + tid * 8);
    load_lds16(b1 + kt, Bs + (256 + tid) * 8);
    __syncthreads();
    bf16x8 af[4], bfr[4];
#pragma unroll
    for (int i = 0; i < 4; i++)
      af[i] = *(const bf16x8*)(As + (mw + i * 16 + lrow) * 32 + quad * 8);
#pragma unroll
    for (int j = 0; j < 4; j++)
      bfr[j] = *(const bf16x8*)(Bs + (nw + j * 16 + lrow) * 32 + quad * 8);
#pragma unroll
    for (int i = 0; i < 4; i++)
#pragma unroll
      for (int j = 0; j < 4; j++)
        acc[i][j] = __builtin_amdgcn_mfma_f32_16x16x32_bf16(af[i], bfr[j], acc[i][j], 0, 0, 0);
    __syncthreads();
  }
}

// ---------------- GEMM1: qkv. Q/K scatter epilogue; V-tiles transpose in LDS -> Vt ----------------
__global__ __launch_bounds__(256, 3) void gemm_qkv(const unsigned short* __restrict__ A,
                                                   const unsigned short* __restrict__ Bt,
                                                   unsigned short* __restrict__ Qb,
                                                   unsigned short* __restrict__ Kb,
                                                   unsigned short* __restrict__ Vtb) {
  __shared__ unsigned short smem[2 * 128 * 32];
  unsigned short* As = smem;
  unsigned short* Bs = smem + 128 * 32;
  f32x4 acc[4][4];
  f32x4 z = {0.f, 0.f, 0.f, 0.f};
#pragma unroll
  for (int i = 0; i < 4; i++)
#pragma unroll
    for (int j = 0; j < 4; j++) acc[i][j] = z;
  int m0 = blockIdx.x << 7, n0 = blockIdx.y << 7;
  gemm_mainloop(A, Bt, m0, n0, As, Bs, acc);
  int tid = threadIdx.x, wv = tid >> 6, ln = tid & 63, quad = ln >> 4, lrow = ln & 15;
  int mw_l = (wv >> 1) << 6, nw_l = (wv & 1) << 6;
  int bb = m0 >> 11;  // batch (tiles never straddle: 2048 % 128 == 0)
  int which = n0 / DM_;       // block-uniform: 0=Q 1=K 2=V
  int nrem0 = n0 - which * DM_;
  if (which < 2) {
    unsigned short* dstp = which == 0 ? Qb : Kb;
#pragma unroll
    for (int j = 0; j < 4; j++) {
      int nb = nrem0 + nw_l + j * 16;
      int h = nb >> 6, hdb = (nb & 63) + lrow;
      size_t hoff = (size_t)(bb * NH_ + h) << 11;
#pragma unroll
      for (int i = 0; i < 4; i++)
#pragma unroll
        for (int r = 0; r < 4; r++) {
          int s = (m0 + mw_l + i * 16 + quad * 4 + r) & (SEQ_ - 1);
          dstp[((hoff + s) << 6) + hdb] = f2bf(acc[i][j][r]);
        }
    }
  } else {
    // V: transpose each 128s x 32hd j-slice through LDS, write Vt[bh][hd][s] coalesced
    const int LSTR = 136;  // shorts; mult of 8 for aligned b128 reads
    int hdl2 = ((wv & 1) << 4) + lrow;            // 0..31 within slice
    int hds = tid >> 3, s0 = (tid & 7) << 4;      // copy-out coords
    int hd_in_block = ((hds & 16) << 2) + (hds & 15);  // +j*16 later
#pragma unroll
    for (int j = 0; j < 4; j++) {
      __syncthreads();
#pragma unroll
      for (int i = 0; i < 4; i++)
#pragma unroll
        for (int r = 0; r < 4; r++) {
          int sl = mw_l + i * 16 + quad * 4 + r;
          smem[hdl2 * LSTR + sl] = f2bf(acc[i][j][r]);
        }
      __syncthreads();
      int nb = nrem0 + hd_in_block + j * 16;   // 0..767
      int h = nb >> 6, hdh = nb & 63;
      uint4 p0 = *(const uint4*)&smem[hds * LSTR + s0];
      uint4 p1 = *(const uint4*)&smem[hds * LSTR + s0 + 8];
      size_t vbase = (size_t)(((bb * NH_ + h) << 6) + hdh) * SEQ_ + (m0 & (SEQ_ - 1)) + s0;
      *(uint4*)(Vtb + vbase) = p0;
      *(uint4*)(Vtb + vbase + 8) = p1;
    }
  }
}

// ---------------- GEMM2: out(fp32) = attn_bf @ Wo_t^T, 64x128 tiles ----------------
__global__ __launch_bounds__(256, 3) void gemm_out(const unsigned short* __restrict__ A,
                                                   const unsigned short* __restrict__ Bt,
                                                   float* __restrict__ out) {
  const int K = 768;
  __shared__ unsigned short As[64 * 32];
  __shared__ unsigned short Bs[128 * 32];
  f32x4 acc[4][2];
  f32x4 z = {0.f, 0.f, 0.f, 0.f};
#pragma unroll
  for (int i = 0; i < 4; i++)
#pragma unroll
    for (int j = 0; j < 2; j++) acc[i][j] = z;
  int m0 = blockIdx.x << 6, n0 = blockIdx.y << 7;
  int tid = threadIdx.x, wv = tid >> 6, ln = tid & 63, quad = ln >> 4, lrow = ln & 15;
  const unsigned short* a0 = A + (size_t)(m0 + (tid >> 2)) * K + (tid & 3) * 8;
  const unsigned short* b0 = Bt + (size_t)(n0 + (tid >> 2)) * K + (tid & 3) * 8;
  const unsigned short* b1 = b0 + (size_t)64 * K;
  int nw = wv << 5;
  for (int kt = 0; kt < K; kt += 32) {
    load_lds16(a0 + kt, As + tid * 8);
    load_lds16(b0 + kt, Bs + tid * 8);
    load_lds16(b1 + kt, Bs + (256 + tid) * 8);
    __syncthreads();
    bf16x8 af[4], bfr[2];
#pragma unroll
    for (int i = 0; i < 4; i++)
      af[i] = *(const bf16x8*)(As + (i * 16 + lrow) * 32 + quad * 8);
#pragma unroll
    for (int j = 0; j < 2; j++)
      bfr[j] = *(const bf16x8*)(Bs + (nw + j * 16 + lrow) * 32 + quad * 8);
#pragma unroll
    for (int i = 0; i < 4; i++)
#pragma unroll
      for (int j = 0; j < 2; j++)
        acc[i][j] = __builtin_amdgcn_mfma_f32_16x16x32_bf16(af[i], bfr[j], acc[i][j], 0, 0, 0);
    __syncthreads();
  }
#pragma unroll
  for (int i = 0; i < 4; i++)
#pragma unroll
    for (int j = 0; j < 2; j++)
#pragma unroll
      for (int r = 0; r < 4; r++)
        out[(size_t)(m0 + i * 16 + quad * 4 + r) * DM_ + n0 + nw + j * 16 + lrow] = acc[i][j][r];
}

// ---------------- windowed attention ----------------
__global__ __launch_bounds__(256, 3) void attn_kernel(const unsigned short* __restrict__ Qb,
                                                      const unsigned short* __restrict__ Kb,
                                                      const unsigned short* __restrict__ Vtb,
                                                      const float* __restrict__ pmask,
                                                      unsigned short* __restrict__ Obf) {
  __shared__ unsigned short Ps[4][16 * 168];  // per-wave P, padded stride 168
  int blk = blockIdx.x;
  int tile = blk & 31, bh = blk >> 5;
  int b = bh / NH_, h = bh % NH_;
  int q0 = tile << 6;
  int kstart = q0 - 64;
  int tid = threadIdx.x, wv = tid >> 6, ln = tid & 63, quad = ln >> 4, lrow = ln & 15;
  int kb = wv << 4;
  int qw = q0 + (wv << 4);

  const unsigned short* Qg = Qb + ((size_t)bh << 11) * 64;
  const unsigned short* Kg = Kb + ((size_t)bh << 11) * 64;
  const unsigned short* Vg = Vtb + ((size_t)bh << 6) * SEQ_;

  bf16x8 qf0 = *(const bf16x8*)(Qg + (qw + lrow) * 64 + quad * 8);
  bf16x8 qf1 = *(const bf16x8*)(Qg + (qw + lrow) * 64 + 32 + quad * 8);

  float sc[9][4];
#pragma unroll
  for (int t = 0; t < 9; t++) {
    int kg = kstart + kb + t * 16 + lrow;
    int kgc = kg < 0 ? 0 : (kg > SEQ_ - 1 ? SEQ_ - 1 : kg);
    bf16x8 kf0 = *(const bf16x8*)(Kg + (size_t)kgc * 64 + quad * 8);
    bf16x8 kf1 = *(const bf16x8*)(Kg + (size_t)kgc * 64 + 32 + quad * 8);
    f32x4 c = {0.f, 0.f, 0.f, 0.f};
    c = __builtin_amdgcn_mfma_f32_16x16x32_bf16(qf0, kf0, c, 0, 0, 0);
    c = __builtin_amdgcn_mfma_f32_16x16x32_bf16(qf1, kf1, c, 0, 0, 0);
    float mneg = -1e30f;
    if (kg >= 0 && kg < SEQ_) {
      if (pmask[(b << 11) + kg] != 0.0f) mneg = 0.0f;
    }
#pragma unroll
    for (int r = 0; r < 4; r++) {
      int qg = qw + quad * 4 + r;
      int d = qg - kg;
      float wneg = (d >= -64 && d <= 64) ? 0.0f : -1e30f;
      sc[t][r] = c[r] * 0.125f + mneg + wneg;
    }
  }
  float inv[4];
#pragma unroll
  for (int r = 0; r < 4; r++) {
    float mx = sc[0][r];
#pragma unroll
    for (int t = 1; t < 9; t++) mx = fmaxf(mx, sc[t][r]);
    mx = fmaxf(mx, __shfl_xor(mx, 1));
    mx = fmaxf(mx, __shfl_xor(mx, 2));
    mx = fmaxf(mx, __shfl_xor(mx, 4));
    mx = fmaxf(mx, __shfl_xor(mx, 8));
    float s = 0.f;
#pragma unroll
    for (int t = 0; t < 9; t++) {
      sc[t][r] = __expf(sc[t][r] - mx);
      s += sc[t][r];
    }
    s += __shfl_xor(s, 1);
    s += __shfl_xor(s, 2);
    s += __shfl_xor(s, 4);
    s += __shfl_xor(s, 8);
    inv[r] = 1.0f / s;
  }
  unsigned short* Pw = &Ps[wv][0];
#pragma unroll
  for (int t = 0; t < 9; t++)
#pragma unroll
    for (int r = 0; r < 4; r++)
      Pw[(quad * 4 + r) * 168 + t * 16 + lrow] = f2bf(sc[t][r] * inv[r]);
  {
    int row = ln >> 2, c0 = 144 + (ln & 3) * 4;
    uint2 zz; zz.x = 0; zz.y = 0;
    *(uint2*)(Pw + row * 168 + c0) = zz;
  }
  __syncthreads();
  f32x4 o[4];
  f32x4 z = {0.f, 0.f, 0.f, 0.f};
#pragma unroll
  for (int tt = 0; tt < 4; tt++) o[tt] = z;
#pragma unroll
  for (int ks = 0; ks < 5; ks++) {
    bf16x8 pf = *(const bf16x8*)(Pw + lrow * 168 + ks * 32 + quad * 8);
    int kg = kstart + kb + ks * 32 + quad * 8;
    int kgc = kg < 0 ? 0 : (kg > SEQ_ - 8 ? SEQ_ - 8 : kg);
#pragma unroll
    for (int tt = 0; tt < 4; tt++) {
      bf16x8 vf = *(const bf16x8*)(Vg + (size_t)(tt * 16 + lrow) * SEQ_ + kgc);
      o[tt] = __builtin_amdgcn_mfma_f32_16x16x32_bf16(pf, vf, o[tt], 0, 0, 0);
    }
  }
#pragma unroll
  for (int tt = 0; tt < 4; tt++)
#pragma unroll
    for (int r = 0; r < 4; r++) {
      int s_ = qw + quad * 4 + r;
      Obf[((size_t)(b << 11) + s_) * DM_ + h * 64 + tt * 16 + lrow] = f2bf(o[tt][r]);
    }
}

extern "C" void kernel_launch(void* const* d_in, const int* in_sizes, int n_in,
                              void* d_out, int out_size, void* d_ws, size_t ws_size,
                              hipStream_t stream) {
  const float* x = (const float*)d_in[0];
  const float* pmask = (const float*)d_in[1];
  const float* Wqkv = (const float*)d_in[2];
  const float* Wo = (const float*)d_in[3];
  float* out = (float*)d_out;
  char* ws = (char*)d_ws;

  unsigned short* xb    = (unsigned short*)(ws + 0);         // 4096*768*2   = 6291456
  unsigned short* wqkvt = (unsigned short*)(ws + 6291456);   // 2304*768*2   = 3538944
  unsigned short* wot   = (unsigned short*)(ws + 9830400);   // 768*768*2    = 1179648
  unsigned short* Qb    = (unsigned short*)(ws + 11010048);  // 24*2048*64*2 = 6291456
  unsigned short* Kb    = (unsigned short*)(ws + 17301504);
  unsigned short* Vtb   = (unsigned short*)(ws + 23592960);  // end 29884416
  unsigned short* attn_bf = xb;  // xb dead after gemm_qkv; reuse

  prep<<<3648, 256, 0, stream>>>(x, Wqkv, Wo, xb, wqkvt, wot);
  gemm_qkv<<<dim3(32, 18), 256, 0, stream>>>(xb, wqkvt, Qb, Kb, Vtb);
  attn_kernel<<<768, 256, 0, stream>>>(Qb, Kb, Vtb, pmask, attn_bf);
  gemm_out<<<dim3(64, 6), 256, 0, stream>>>(attn_bf, wot, out);
}

// Round 3
// 128.839 us; speedup vs baseline: 1.1177x; 1.0446x over previous
//
#include <hip/hip_runtime.h>
#include <stdint.h>

typedef short bf16x8 __attribute__((ext_vector_type(8)));
typedef float f32x4 __attribute__((ext_vector_type(4)));

#define SEQ_ 2048
#define DM_ 768
#define NH_ 12

__device__ __forceinline__ unsigned short f2bf(float f) {
  unsigned int u = __float_as_uint(f);
  u += 0x7fffu + ((u >> 16) & 1u);
  return (unsigned short)(u >> 16);
}

__device__ __forceinline__ void load_lds16(const unsigned short* g, unsigned short* l) {
  __builtin_amdgcn_global_load_lds((__attribute__((address_space(1))) void*)g,
                                   (__attribute__((address_space(3))) void*)l, 16, 0, 0);
}

// ---------------- prep: x->bf16 cast + Wqkv/Wo transpose+cast, one kernel ----------------
__device__ __forceinline__ void transpose_body(const float* __restrict__ src,
                                               unsigned short* __restrict__ dst,
                                               int R, int C, int bx, int by,
                                               float (*t)[65]) {
  int c0 = bx << 6, r0 = by << 6;
  int tid = threadIdx.x;
#pragma unroll
  for (int i = 0; i < 4; i++) {
    int e = (i * 256 + tid) * 4;
    int r = e >> 6, c = e & 63;
    float4 v = *(const float4*)(src + (size_t)(r0 + r) * C + c0 + c);
    t[r][c] = v.x; t[r][c + 1] = v.y; t[r][c + 2] = v.z; t[r][c + 3] = v.w;
  }
  __syncthreads();
#pragma unroll
  for (int i = 0; i < 4; i++) {
    int e = (i * 256 + tid) * 4;
    int r = e >> 6, c = e & 63;
    unsigned short o4[4];
#pragma unroll
    for (int j = 0; j < 4; j++) o4[j] = f2bf(t[c + j][r]);
    *(uint2*)(dst + (size_t)(c0 + r) * R + r0 + c) = *(const uint2*)o4;
  }
}

__global__ __launch_bounds__(256) void prep(const float* __restrict__ x,
                                            const float* __restrict__ Wqkv,
                                            const float* __restrict__ Wo,
                                            unsigned short* __restrict__ xb,
                                            unsigned short* __restrict__ wqkvt,
                                            unsigned short* __restrict__ wot) {
  __shared__ float t[64][65];
  int blk = blockIdx.x;
  if (blk < 3072) {
    int i = (blk * 256 + threadIdx.x) * 4;
    float4 v = *(const float4*)(x + i);
    unsigned short o[4] = {f2bf(v.x), f2bf(v.y), f2bf(v.z), f2bf(v.w)};
    *(uint2*)(xb + i) = *(const uint2*)o;
  } else if (blk < 3072 + 432) {
    int idx = blk - 3072;
    transpose_body(Wqkv, wqkvt, DM_, 3 * DM_, idx % 36, idx / 36, t);
  } else {
    int idx = blk - 3504;
    transpose_body(Wo, wot, DM_, DM_, idx % 12, idx / 12, t);
  }
}

// ---------------- GEMM mainloop, BK=64, XOR-swizzled LDS ----------------
// LDS layout: row r (0..127), 8 chunks of 16B per row; global k-chunk g stored at
// chunk index g ^ (r&7). Staging permutes each lane's GLOBAL column (LDS dest is
// fixed to lane*16B by global_load_lds).
__device__ __forceinline__ void gemm_mainloop(const unsigned short* __restrict__ A,
                                              const unsigned short* __restrict__ Bt,
                                              int m0, int n0,
                                              unsigned short* As, unsigned short* Bs,
                                              f32x4 acc[4][4]) {
  const int K = 768;
  int tid = threadIdx.x, wv = tid >> 6, ln = tid & 63, quad = ln >> 4, lrow = ln & 15;
  int row = tid >> 3;
  int col8 = (tid & 7) ^ (row & 7);  // swizzled global k-chunk
  const unsigned short* a0 = A + (size_t)(m0 + row) * K + col8 * 8;
  const unsigned short* b0 = Bt + (size_t)(n0 + row) * K + col8 * 8;
  int mw = (wv >> 1) << 6, nw = (wv & 1) << 6;
  int sw = (lrow & 7);
  for (int kt = 0; kt < K; kt += 64) {
#pragma unroll
    for (int st = 0; st < 4; st++) {
      load_lds16(a0 + (size_t)(st * 32) * K + kt, As + (st * 256 + tid) * 8);
      load_lds16(b0 + (size_t)(st * 32) * K + kt, Bs + (st * 256 + tid) * 8);
    }
    __syncthreads();
#pragma unroll
    for (int ks = 0; ks < 2; ks++) {
      bf16x8 af[4], bfr[4];
#pragma unroll
      for (int i = 0; i < 4; i++)
        af[i] = *(const bf16x8*)(As + (mw + i * 16 + lrow) * 64 + (((ks * 4 + quad) ^ sw) << 3));
#pragma unroll
      for (int j = 0; j < 4; j++)
        bfr[j] = *(const bf16x8*)(Bs + (nw + j * 16 + lrow) * 64 + (((ks * 4 + quad) ^ sw) << 3));
#pragma unroll
      for (int i = 0; i < 4; i++)
#pragma unroll
        for (int j = 0; j < 4; j++)
          acc[i][j] = __builtin_amdgcn_mfma_f32_16x16x32_bf16(af[i], bfr[j], acc[i][j], 0, 0, 0);
    }
    __syncthreads();
  }
}

// ---------------- GEMM1: qkv. Q/K scatter epilogue; V-tiles transpose in LDS -> Vt ----------------
__global__ __launch_bounds__(256, 3) void gemm_qkv(const unsigned short* __restrict__ A,
                                                   const unsigned short* __restrict__ Bt,
                                                   unsigned short* __restrict__ Qb,
                                                   unsigned short* __restrict__ Kb,
                                                   unsigned short* __restrict__ Vtb) {
  __shared__ unsigned short smem[2 * 128 * 64];
  unsigned short* As = smem;
  unsigned short* Bs = smem + 128 * 64;
  f32x4 acc[4][4];
  f32x4 z = {0.f, 0.f, 0.f, 0.f};
#pragma unroll
  for (int i = 0; i < 4; i++)
#pragma unroll
    for (int j = 0; j < 4; j++) acc[i][j] = z;
  int m0 = blockIdx.x << 7, n0 = blockIdx.y << 7;
  gemm_mainloop(A, Bt, m0, n0, As, Bs, acc);
  int tid = threadIdx.x, wv = tid >> 6, ln = tid & 63, quad = ln >> 4, lrow = ln & 15;
  int mw_l = (wv >> 1) << 6, nw_l = (wv & 1) << 6;
  int bb = m0 >> 11;  // batch (tiles never straddle: 2048 % 128 == 0)
  int which = n0 / DM_;       // block-uniform: 0=Q 1=K 2=V
  int nrem0 = n0 - which * DM_;
  if (which < 2) {
    unsigned short* dstp = which == 0 ? Qb : Kb;
#pragma unroll
    for (int j = 0; j < 4; j++) {
      int nb = nrem0 + nw_l + j * 16;
      int h = nb >> 6, hdb = (nb & 63) + lrow;
      size_t hoff = (size_t)(bb * NH_ + h) << 11;
#pragma unroll
      for (int i = 0; i < 4; i++)
#pragma unroll
        for (int r = 0; r < 4; r++) {
          int s = (m0 + mw_l + i * 16 + quad * 4 + r) & (SEQ_ - 1);
          dstp[((hoff + s) << 6) + hdb] = f2bf(acc[i][j][r]);
        }
    }
  } else {
    // V: transpose each 128s x 32hd j-slice through LDS, write Vt[bh][hd][s] coalesced
    const int LSTR = 136;  // shorts; mult of 8 for aligned b128 reads
    int hdl2 = ((wv & 1) << 4) + lrow;            // 0..31 within slice
    int hds = tid >> 3, s0 = (tid & 7) << 4;      // copy-out coords
    int hd_in_block = ((hds & 16) << 2) + (hds & 15);  // +j*16 later
#pragma unroll
    for (int j = 0; j < 4; j++) {
      __syncthreads();
#pragma unroll
      for (int i = 0; i < 4; i++)
#pragma unroll
        for (int r = 0; r < 4; r++) {
          int sl = mw_l + i * 16 + quad * 4 + r;
          smem[hdl2 * LSTR + sl] = f2bf(acc[i][j][r]);
        }
      __syncthreads();
      int nb = nrem0 + hd_in_block + j * 16;   // 0..767
      int h = nb >> 6, hdh = nb & 63;
      uint4 p0 = *(const uint4*)&smem[hds * LSTR + s0];
      uint4 p1 = *(const uint4*)&smem[hds * LSTR + s0 + 8];
      size_t vbase = (size_t)(((bb * NH_ + h) << 6) + hdh) * SEQ_ + (m0 & (SEQ_ - 1)) + s0;
      *(uint4*)(Vtb + vbase) = p0;
      *(uint4*)(Vtb + vbase + 8) = p1;
    }
  }
}

// ---------------- GEMM2: out(fp32) = attn_bf @ Wo_t^T, 128x96 tiles, 256 blocks ----------------
__global__ __launch_bounds__(256, 3) void gemm_out(const unsigned short* __restrict__ A,
                                                   const unsigned short* __restrict__ Bt,
                                                   float* __restrict__ out) {
  const int K = 768;
  __shared__ unsigned short As[128 * 64];
  __shared__ unsigned short Bs[96 * 64];
  f32x4 acc[4][3];
  f32x4 z = {0.f, 0.f, 0.f, 0.f};
#pragma unroll
  for (int i = 0; i < 4; i++)
#pragma unroll
    for (int j = 0; j < 3; j++) acc[i][j] = z;
  int m0 = blockIdx.x << 7, n0 = blockIdx.y * 96;
  int tid = threadIdx.x, wv = tid >> 6, ln = tid & 63, quad = ln >> 4, lrow = ln & 15;
  int row = tid >> 3;
  int col8 = (tid & 7) ^ (row & 7);
  const unsigned short* a0 = A + (size_t)(m0 + row) * K + col8 * 8;
  const unsigned short* b0 = Bt + (size_t)(n0 + row) * K + col8 * 8;
  int mw = (wv >> 1) << 6, nw = (wv & 1) * 48;
  int sw = (lrow & 7);
  for (int kt = 0; kt < K; kt += 64) {
#pragma unroll
    for (int st = 0; st < 4; st++)
      load_lds16(a0 + (size_t)(st * 32) * K + kt, As + (st * 256 + tid) * 8);
#pragma unroll
    for (int st = 0; st < 3; st++)
      load_lds16(b0 + (size_t)(st * 32) * K + kt, Bs + (st * 256 + tid) * 8);
    __syncthreads();
#pragma unroll
    for (int ks = 0; ks < 2; ks++) {
      bf16x8 af[4], bfr[3];
#pragma unroll
      for (int i = 0; i < 4; i++)
        af[i] = *(const bf16x8*)(As + (mw + i * 16 + lrow) * 64 + (((ks * 4 + quad) ^ sw) << 3));
#pragma unroll
      for (int j = 0; j < 3; j++)
        bfr[j] = *(const bf16x8*)(Bs + (nw + j * 16 + lrow) * 64 + (((ks * 4 + quad) ^ sw) << 3));
#pragma unroll
      for (int i = 0; i < 4; i++)
#pragma unroll
        for (int j = 0; j < 3; j++)
          acc[i][j] = __builtin_amdgcn_mfma_f32_16x16x32_bf16(af[i], bfr[j], acc[i][j], 0, 0, 0);
    }
    __syncthreads();
  }
#pragma unroll
  for (int i = 0; i < 4; i++)
#pragma unroll
    for (int j = 0; j < 3; j++)
#pragma unroll
      for (int r = 0; r < 4; r++)
        out[(size_t)(m0 + mw + i * 16 + quad * 4 + r) * DM_ + n0 + nw + j * 16 + lrow] = acc[i][j][r];
}

// ---------------- windowed attention ----------------
__global__ __launch_bounds__(256, 3) void attn_kernel(const unsigned short* __restrict__ Qb,
                                                      const unsigned short* __restrict__ Kb,
                                                      const unsigned short* __restrict__ Vtb,
                                                      const float* __restrict__ pmask,
                                                      unsigned short* __restrict__ Obf) {
  __shared__ unsigned short Ps[4][16 * 168];  // per-wave P, padded stride 168
  int blk = blockIdx.x;
  int tile = blk & 31, bh = blk >> 5;
  int b = bh / NH_, h = bh % NH_;
  int q0 = tile << 6;
  int kstart = q0 - 64;
  int tid = threadIdx.x, wv = tid >> 6, ln = tid & 63, quad = ln >> 4, lrow = ln & 15;
  int kb = wv << 4;
  int qw = q0 + (wv << 4);

  const unsigned short* Qg = Qb + ((size_t)bh << 11) * 64;
  const unsigned short* Kg = Kb + ((size_t)bh << 11) * 64;
  const unsigned short* Vg = Vtb + ((size_t)bh << 6) * SEQ_;

  bf16x8 qf0 = *(const bf16x8*)(Qg + (qw + lrow) * 64 + quad * 8);
  bf16x8 qf1 = *(const bf16x8*)(Qg + (qw + lrow) * 64 + 32 + quad * 8);

  float sc[9][4];
#pragma unroll
  for (int t = 0; t < 9; t++) {
    int kg = kstart + kb + t * 16 + lrow;
    int kgc = kg < 0 ? 0 : (kg > SEQ_ - 1 ? SEQ_ - 1 : kg);
    bf16x8 kf0 = *(const bf16x8*)(Kg + (size_t)kgc * 64 + quad * 8);
    bf16x8 kf1 = *(const bf16x8*)(Kg + (size_t)kgc * 64 + 32 + quad * 8);
    f32x4 c = {0.f, 0.f, 0.f, 0.f};
    c = __builtin_amdgcn_mfma_f32_16x16x32_bf16(qf0, kf0, c, 0, 0, 0);
    c = __builtin_amdgcn_mfma_f32_16x16x32_bf16(qf1, kf1, c, 0, 0, 0);
    float mneg = -1e30f;
    if (kg >= 0 && kg < SEQ_) {
      if (pmask[(b << 11) + kg] != 0.0f) mneg = 0.0f;
    }
#pragma unroll
    for (int r = 0; r < 4; r++) {
      int qg = qw + quad * 4 + r;
      int d = qg - kg;
      float wneg = (d >= -64 && d <= 64) ? 0.0f : -1e30f;
      sc[t][r] = c[r] * 0.125f + mneg + wneg;
    }
  }
  float inv[4];
#pragma unroll
  for (int r = 0; r < 4; r++) {
    float mx = sc[0][r];
#pragma unroll
    for (int t = 1; t < 9; t++) mx = fmaxf(mx, sc[t][r]);
    mx = fmaxf(mx, __shfl_xor(mx, 1));
    mx = fmaxf(mx, __shfl_xor(mx, 2));
    mx = fmaxf(mx, __shfl_xor(mx, 4));
    mx = fmaxf(mx, __shfl_xor(mx, 8));
    float s = 0.f;
#pragma unroll
    for (int t = 0; t < 9; t++) {
      sc[t][r] = __expf(sc[t][r] - mx);
      s += sc[t][r];
    }
    s += __shfl_xor(s, 1);
    s += __shfl_xor(s, 2);
    s += __shfl_xor(s, 4);
    s += __shfl_xor(s, 8);
    inv[r] = 1.0f / s;
  }
  unsigned short* Pw = &Ps[wv][0];
#pragma unroll
  for (int t = 0; t < 9; t++)
#pragma unroll
    for (int r = 0; r < 4; r++)
      Pw[(quad * 4 + r) * 168 + t * 16 + lrow] = f2bf(sc[t][r] * inv[r]);
  {
    int row = ln >> 2, c0 = 144 + (ln & 3) * 4;
    uint2 zz; zz.x = 0; zz.y = 0;
    *(uint2*)(Pw + row * 168 + c0) = zz;
  }
  __syncthreads();
  f32x4 o[4];
  f32x4 z = {0.f, 0.f, 0.f, 0.f};
#pragma unroll
  for (int tt = 0; tt < 4; tt++) o[tt] = z;
#pragma unroll
  for (int ks = 0; ks < 5; ks++) {
    bf16x8 pf = *(const bf16x8*)(Pw + lrow * 168 + ks * 32 + quad * 8);
    int kg = kstart + kb + ks * 32 + quad * 8;
    int kgc = kg < 0 ? 0 : (kg > SEQ_ - 8 ? SEQ_ - 8 : kg);
#pragma unroll
    for (int tt = 0; tt < 4; tt++) {
      bf16x8 vf = *(const bf16x8*)(Vg + (size_t)(tt * 16 + lrow) * SEQ_ + kgc);
      o[tt] = __builtin_amdgcn_mfma_f32_16x16x32_bf16(pf, vf, o[tt], 0, 0, 0);
    }
  }
#pragma unroll
  for (int tt = 0; tt < 4; tt++)
#pragma unroll
    for (int r = 0; r < 4; r++) {
      int s_ = qw + quad * 4 + r;
      Obf[((size_t)(b << 11) + s_) * DM_ + h * 64 + tt * 16 + lrow] = f2bf(o[tt][r]);
    }
}

extern "C" void kernel_launch(void* const* d_in, const int* in_sizes, int n_in,
                              void* d_out, int out_size, void* d_ws, size_t ws_size,
                              hipStream_t stream) {
  const float* x = (const float*)d_in[0];
  const float* pmask = (const float*)d_in[1];
  const float* Wqkv = (const float*)d_in[2];
  const float* Wo = (const float*)d_in[3];
  float* out = (float*)d_out;
  char* ws = (char*)d_ws;

  unsigned short* xb    = (unsigned short*)(ws + 0);         // 4096*768*2   = 6291456
  unsigned short* wqkvt = (unsigned short*)(ws + 6291456);   // 2304*768*2   = 3538944
  unsigned short* wot   = (unsigned short*)(ws + 9830400);   // 768*768*2    = 1179648
  unsigned short* Qb    = (unsigned short*)(ws + 11010048);  // 24*2048*64*2 = 6291456
  unsigned short* Kb    = (unsigned short*)(ws + 17301504);
  unsigned short* Vtb   = (unsigned short*)(ws + 23592960);  // end 29884416
  unsigned short* attn_bf = xb;  // xb dead after gemm_qkv; reuse

  prep<<<3648, 256, 0, stream>>>(x, Wqkv, Wo, xb, wqkvt, wot);
  gemm_qkv<<<dim3(32, 18), 256, 0, stream>>>(xb, wqkvt, Qb, Kb, Vtb);
  attn_kernel<<<768, 256, 0, stream>>>(Qb, Kb, Vtb, pmask, attn_bf);
  gemm_out<<<dim3(32, 8), 256, 0, stream>>>(attn_bf, wot, out);
}

// Round 5
// 122.232 us; speedup vs baseline: 1.1781x; 1.0541x over previous
//
#include <hip/hip_runtime.h>
#include <stdint.h>

typedef short bf16x8 __attribute__((ext_vector_type(8)));
typedef float f32x4 __attribute__((ext_vector_type(4)));

#define SEQ_ 2048
#define DM_ 768
#define NH_ 12

__device__ __forceinline__ unsigned short f2bf(float f) {
  unsigned int u = __float_as_uint(f);
  u += 0x7fffu + ((u >> 16) & 1u);
  return (unsigned short)(u >> 16);
}

__device__ __forceinline__ void load_lds16(const unsigned short* g, unsigned short* l) {
  __builtin_amdgcn_global_load_lds((__attribute__((address_space(1))) void*)g,
                                   (__attribute__((address_space(3))) void*)l, 16, 0, 0);
}

// ---------------- prep: x->bf16 cast + Wqkv/Wo transpose+cast ----------------
__device__ __forceinline__ void transpose_body(const float* __restrict__ src,
                                               unsigned short* __restrict__ dst,
                                               int R, int C, int bx, int by,
                                               float (*t)[65]) {
  int c0 = bx << 6, r0 = by << 6;
  int tid = threadIdx.x;
#pragma unroll
  for (int i = 0; i < 4; i++) {
    int e = (i * 256 + tid) * 4;
    int r = e >> 6, c = e & 63;
    float4 v = *(const float4*)(src + (size_t)(r0 + r) * C + c0 + c);
    t[r][c] = v.x; t[r][c + 1] = v.y; t[r][c + 2] = v.z; t[r][c + 3] = v.w;
  }
  __syncthreads();
#pragma unroll
  for (int i = 0; i < 4; i++) {
    int e = (i * 256 + tid) * 4;
    int r = e >> 6, c = e & 63;
    unsigned short o4[4];
#pragma unroll
    for (int j = 0; j < 4; j++) o4[j] = f2bf(t[c + j][r]);
    *(uint2*)(dst + (size_t)(c0 + r) * R + r0 + c) = *(const uint2*)o4;
  }
}

__global__ __launch_bounds__(256) void prep(const float* __restrict__ x,
                                            const float* __restrict__ Wqkv,
                                            const float* __restrict__ Wo,
                                            unsigned short* __restrict__ xb,
                                            unsigned short* __restrict__ wqkvt,
                                            unsigned short* __restrict__ wot) {
  __shared__ float t[64][65];
  int blk = blockIdx.x;
  if (blk < 3072) {
    int i = (blk * 256 + threadIdx.x) * 4;
    float4 v = *(const float4*)(x + i);
    unsigned short o[4] = {f2bf(v.x), f2bf(v.y), f2bf(v.z), f2bf(v.w)};
    *(uint2*)(xb + i) = *(const uint2*)o;
  } else if (blk < 3072 + 432) {
    int idx = blk - 3072;
    transpose_body(Wqkv, wqkvt, DM_, 3 * DM_, idx % 36, idx / 36, t);
  } else {
    int idx = blk - 3504;
    transpose_body(Wo, wot, DM_, DM_, idx % 12, idx / 12, t);
  }
}

// ---------------- GEMM1: 128x96 tiles, 768 blocks (perfect 3/CU fill) ----------------
// BK=64 XOR-swizzled LDS (chunk g of row r at slot g^(r&7)).
__global__ __launch_bounds__(256, 3) void gemm_qkv(const unsigned short* __restrict__ A,
                                                   const unsigned short* __restrict__ Bt,
                                                   unsigned short* __restrict__ Qb,
                                                   unsigned short* __restrict__ Kb,
                                                   unsigned short* __restrict__ Vtb) {
  const int K = 768;
  __shared__ unsigned short smem[128 * 64 + 96 * 64];
  unsigned short* As = smem;
  unsigned short* Bs = smem + 128 * 64;
  f32x4 acc[4][3];
  f32x4 z = {0.f, 0.f, 0.f, 0.f};
#pragma unroll
  for (int i = 0; i < 4; i++)
#pragma unroll
    for (int j = 0; j < 3; j++) acc[i][j] = z;
  int m0 = blockIdx.x << 7, n0 = blockIdx.y * 96;
  int tid = threadIdx.x, wv = tid >> 6, ln = tid & 63, quad = ln >> 4, lrow = ln & 15;
  int row = tid >> 3;
  int col8 = (tid & 7) ^ (row & 7);
  const unsigned short* a0 = A + (size_t)(m0 + row) * K + col8 * 8;
  const unsigned short* b0 = Bt + (size_t)(n0 + row) * K + col8 * 8;
  int mw = (wv >> 1) << 6, nw = (wv & 1) * 48;
  int sw = lrow & 7;
  for (int kt = 0; kt < K; kt += 64) {
#pragma unroll
    for (int st = 0; st < 4; st++)
      load_lds16(a0 + (size_t)(st * 32) * K + kt, As + (st * 256 + tid) * 8);
#pragma unroll
    for (int st = 0; st < 3; st++)
      load_lds16(b0 + (size_t)(st * 32) * K + kt, Bs + (st * 256 + tid) * 8);
    __syncthreads();
#pragma unroll
    for (int ks = 0; ks < 2; ks++) {
      bf16x8 af[4], bfr[3];
#pragma unroll
      for (int i = 0; i < 4; i++)
        af[i] = *(const bf16x8*)(As + (mw + i * 16 + lrow) * 64 + (((ks * 4 + quad) ^ sw) << 3));
#pragma unroll
      for (int j = 0; j < 3; j++)
        bfr[j] = *(const bf16x8*)(Bs + (nw + j * 16 + lrow) * 64 + (((ks * 4 + quad) ^ sw) << 3));
#pragma unroll
      for (int i = 0; i < 4; i++)
#pragma unroll
        for (int j = 0; j < 3; j++)
          acc[i][j] = __builtin_amdgcn_mfma_f32_16x16x32_bf16(af[i], bfr[j], acc[i][j], 0, 0, 0);
    }
    __syncthreads();
  }
  int mw_l = mw, nw_l = nw;
  int bb = m0 >> 11;
  int which = n0 / DM_;  // 8 tiles each: 0=Q 1=K 2=V (block-uniform)
  int nrem0 = n0 - which * DM_;
  if (which < 2) {
    unsigned short* dstp = which == 0 ? Qb : Kb;
#pragma unroll
    for (int j = 0; j < 3; j++) {
      int nb = nrem0 + nw_l + j * 16;
      int h = nb >> 6, hdb = (nb & 63) + lrow;
      size_t hoff = (size_t)(bb * NH_ + h) << 11;
#pragma unroll
      for (int i = 0; i < 4; i++)
#pragma unroll
        for (int r = 0; r < 4; r++) {
          int s = (m0 + mw_l + i * 16 + quad * 4 + r) & (SEQ_ - 1);
          dstp[((hoff + s) << 6) + hdb] = f2bf(acc[i][j][r]);
        }
    }
  } else {
    // V: 3 slices of (128 s x 32 hd) through LDS, write Vt[bh][hd][s] coalesced.
    // Slice j holds cols {j*16+lrow} (waves nw=0, lds rows 0-15) and {48+j*16+lrow} (rows 16-31).
    const int LSTR = 136;
    int hdl2 = ((wv & 1) << 4) + lrow;
    int hds = tid >> 3, s0 = (tid & 7) << 4;
    int hd_in_block = (hds & 16) * 3 + (hds & 15);  // hds>=16 -> 48 + (hds&15)
#pragma unroll
    for (int j = 0; j < 3; j++) {
      __syncthreads();
#pragma unroll
      for (int i = 0; i < 4; i++)
#pragma unroll
        for (int r = 0; r < 4; r++) {
          int sl = mw_l + i * 16 + quad * 4 + r;
          smem[hdl2 * LSTR + sl] = f2bf(acc[i][j][r]);
        }
      __syncthreads();
      int nb = nrem0 + hd_in_block + j * 16;  // 0..767
      int h = nb >> 6, hdh = nb & 63;
      uint4 p0 = *(const uint4*)&smem[hds * LSTR + s0];
      uint4 p1 = *(const uint4*)&smem[hds * LSTR + s0 + 8];
      size_t vbase = (size_t)(((bb * NH_ + h) << 6) + hdh) * SEQ_ + (m0 & (SEQ_ - 1)) + s0;
      *(uint4*)(Vtb + vbase) = p0;
      *(uint4*)(Vtb + vbase + 8) = p1;
    }
  }
}

// ---------------- GEMM2: out(fp32) = attn_bf @ Wo_t^T, 64x96 tiles, 512 blocks (2/CU) ----------------
__global__ __launch_bounds__(256, 3) void gemm_out(const unsigned short* __restrict__ A,
                                                   const unsigned short* __restrict__ Bt,
                                                   float* __restrict__ out) {
  const int K = 768;
  __shared__ unsigned short As[64 * 64];
  __shared__ unsigned short Bs[96 * 64];
  f32x4 acc[2][3];
  f32x4 z = {0.f, 0.f, 0.f, 0.f};
#pragma unroll
  for (int i = 0; i < 2; i++)
#pragma unroll
    for (int j = 0; j < 3; j++) acc[i][j] = z;
  int m0 = blockIdx.x << 6, n0 = blockIdx.y * 96;
  int tid = threadIdx.x, wv = tid >> 6, ln = tid & 63, quad = ln >> 4, lrow = ln & 15;
  int row = tid >> 3;
  int col8 = (tid & 7) ^ (row & 7);
  const unsigned short* a0 = A + (size_t)(m0 + row) * K + col8 * 8;
  const unsigned short* b0 = Bt + (size_t)(n0 + row) * K + col8 * 8;
  int mw = (wv >> 1) << 5, nw = (wv & 1) * 48;
  int sw = lrow & 7;
  for (int kt = 0; kt < K; kt += 64) {
#pragma unroll
    for (int st = 0; st < 2; st++)
      load_lds16(a0 + (size_t)(st * 32) * K + kt, As + (st * 256 + tid) * 8);
#pragma unroll
    for (int st = 0; st < 3; st++)
      load_lds16(b0 + (size_t)(st * 32) * K + kt, Bs + (st * 256 + tid) * 8);
    __syncthreads();
#pragma unroll
    for (int ks = 0; ks < 2; ks++) {
      bf16x8 af[2], bfr[3];
#pragma unroll
      for (int i = 0; i < 2; i++)
        af[i] = *(const bf16x8*)(As + (mw + i * 16 + lrow) * 64 + (((ks * 4 + quad) ^ sw) << 3));
#pragma unroll
      for (int j = 0; j < 3; j++)
        bfr[j] = *(const bf16x8*)(Bs + (nw + j * 16 + lrow) * 64 + (((ks * 4 + quad) ^ sw) << 3));
#pragma unroll
      for (int i = 0; i < 2; i++)
#pragma unroll
        for (int j = 0; j < 3; j++)
          acc[i][j] = __builtin_amdgcn_mfma_f32_16x16x32_bf16(af[i], bfr[j], acc[i][j], 0, 0, 0);
    }
    __syncthreads();
  }
#pragma unroll
  for (int i = 0; i < 2; i++)
#pragma unroll
    for (int j = 0; j < 3; j++)
#pragma unroll
      for (int r = 0; r < 4; r++)
        out[(size_t)(m0 + mw + i * 16 + quad * 4 + r) * DM_ + n0 + nw + j * 16 + lrow] = acc[i][j][r];
}

// ---------------- windowed attention ----------------
__global__ __launch_bounds__(256, 3) void attn_kernel(const unsigned short* __restrict__ Qb,
                                                      const unsigned short* __restrict__ Kb,
                                                      const unsigned short* __restrict__ Vtb,
                                                      const float* __restrict__ pmask,
                                                      unsigned short* __restrict__ Obf) {
  __shared__ unsigned short Ps[4][16 * 168];  // per-wave P, padded stride 168
  int blk = blockIdx.x;
  int tile = blk & 31, bh = blk >> 5;
  int b = bh / NH_, h = bh % NH_;
  int q0 = tile << 6;
  int kstart = q0 - 64;
  int tid = threadIdx.x, wv = tid >> 6, ln = tid & 63, quad = ln >> 4, lrow = ln & 15;
  int kb = wv << 4;
  int qw = q0 + (wv << 4);

  const unsigned short* Qg = Qb + ((size_t)bh << 11) * 64;
  const unsigned short* Kg = Kb + ((size_t)bh << 11) * 64;
  const unsigned short* Vg = Vtb + ((size_t)bh << 6) * SEQ_;

  bf16x8 qf0 = *(const bf16x8*)(Qg + (qw + lrow) * 64 + quad * 8);
  bf16x8 qf1 = *(const bf16x8*)(Qg + (qw + lrow) * 64 + 32 + quad * 8);

  float sc[9][4];
#pragma unroll
  for (int t = 0; t < 9; t++) {
    int kg = kstart + kb + t * 16 + lrow;
    int kgc = kg < 0 ? 0 : (kg > SEQ_ - 1 ? SEQ_ - 1 : kg);
    bf16x8 kf0 = *(const bf16x8*)(Kg + (size_t)kgc * 64 + quad * 8);
    bf16x8 kf1 = *(const bf16x8*)(Kg + (size_t)kgc * 64 + 32 + quad * 8);
    f32x4 c = {0.f, 0.f, 0.f, 0.f};
    c = __builtin_amdgcn_mfma_f32_16x16x32_bf16(qf0, kf0, c, 0, 0, 0);
    c = __builtin_amdgcn_mfma_f32_16x16x32_bf16(qf1, kf1, c, 0, 0, 0);
    float mneg = -1e30f;
    if (kg >= 0 && kg < SEQ_) {
      if (pmask[(b << 11) + kg] != 0.0f) mneg = 0.0f;
    }
#pragma unroll
    for (int r = 0; r < 4; r++) {
      int qg = qw + quad * 4 + r;
      int d = qg - kg;
      float wneg = (d >= -64 && d <= 64) ? 0.0f : -1e30f;
      sc[t][r] = c[r] * 0.125f + mneg + wneg;
    }
  }
  float inv[4];
#pragma unroll
  for (int r = 0; r < 4; r++) {
    float mx = sc[0][r];
#pragma unroll
    for (int t = 1; t < 9; t++) mx = fmaxf(mx, sc[t][r]);
    mx = fmaxf(mx, __shfl_xor(mx, 1));
    mx = fmaxf(mx, __shfl_xor(mx, 2));
    mx = fmaxf(mx, __shfl_xor(mx, 4));
    mx = fmaxf(mx, __shfl_xor(mx, 8));
    float s = 0.f;
#pragma unroll
    for (int t = 0; t < 9; t++) {
      sc[t][r] = __expf(sc[t][r] - mx);
      s += sc[t][r];
    }
    s += __shfl_xor(s, 1);
    s += __shfl_xor(s, 2);
    s += __shfl_xor(s, 4);
    s += __shfl_xor(s, 8);
    inv[r] = 1.0f / s;
  }
  unsigned short* Pw = &Ps[wv][0];
#pragma unroll
  for (int t = 0; t < 9; t++)
#pragma unroll
    for (int r = 0; r < 4; r++)
      Pw[(quad * 4 + r) * 168 + t * 16 + lrow] = f2bf(sc[t][r] * inv[r]);
  {
    int prow = ln >> 2, c0 = 144 + (ln & 3) * 4;
    uint2 zz; zz.x = 0; zz.y = 0;
    *(uint2*)(Pw + prow * 168 + c0) = zz;
  }
  __syncthreads();
  f32x4 o[4];
  f32x4 z = {0.f, 0.f, 0.f, 0.f};
#pragma unroll
  for (int tt = 0; tt < 4; tt++) o[tt] = z;
#pragma unroll
  for (int ks = 0; ks < 5; ks++) {
    bf16x8 pf = *(const bf16x8*)(Pw + lrow * 168 + ks * 32 + quad * 8);
    int kg = kstart + kb + ks * 32 + quad * 8;
    int kgc = kg < 0 ? 0 : (kg > SEQ_ - 8 ? SEQ_ - 8 : kg);
#pragma unroll
    for (int tt = 0; tt < 4; tt++) {
      bf16x8 vf = *(const bf16x8*)(Vg + (size_t)(tt * 16 + lrow) * SEQ_ + kgc);
      o[tt] = __builtin_amdgcn_mfma_f32_16x16x32_bf16(pf, vf, o[tt], 0, 0, 0);
    }
  }
#pragma unroll
  for (int tt = 0; tt < 4; tt++)
#pragma unroll
    for (int r = 0; r < 4; r++) {
      int s_ = qw + quad * 4 + r;
      Obf[((size_t)(b << 11) + s_) * DM_ + h * 64 + tt * 16 + lrow] = f2bf(o[tt][r]);
    }
}

extern "C" void kernel_launch(void* const* d_in, const int* in_sizes, int n_in,
                              void* d_out, int out_size, void* d_ws, size_t ws_size,
                              hipStream_t stream) {
  const float* x = (const float*)d_in[0];
  const float* pmask = (const float*)d_in[1];
  const float* Wqkv = (const float*)d_in[2];
  const float* Wo = (const float*)d_in[3];
  float* out = (float*)d_out;
  char* ws = (char*)d_ws;

  unsigned short* xb    = (unsigned short*)(ws + 0);         // 4096*768*2
  unsigned short* wqkvt = (unsigned short*)(ws + 6291456);   // 2304*768*2
  unsigned short* wot   = (unsigned short*)(ws + 9830400);   // 768*768*2
  unsigned short* Qb    = (unsigned short*)(ws + 11010048);  // 24*2048*64*2
  unsigned short* Kb    = (unsigned short*)(ws + 17301504);
  unsigned short* Vtb   = (unsigned short*)(ws + 23592960);  // end 29884416
  unsigned short* attn_bf = xb;  // xb dead after gemm_qkv; reuse

  prep<<<3648, 256, 0, stream>>>(x, Wqkv, Wo, xb, wqkvt, wot);
  gemm_qkv<<<dim3(32, 24), 256, 0, stream>>>(xb, wqkvt, Qb, Kb, Vtb);
  attn_kernel<<<768, 256, 0, stream>>>(Qb, Kb, Vtb, pmask, attn_bf);
  gemm_out<<<dim3(64, 8), 256, 0, stream>>>(attn_bf, wot, out);
}

// Round 6
// 120.664 us; speedup vs baseline: 1.1934x; 1.0130x over previous
//
#include <hip/hip_runtime.h>
#include <stdint.h>

typedef short bf16x8 __attribute__((ext_vector_type(8)));
typedef float f32x4 __attribute__((ext_vector_type(4)));

#define SEQ_ 2048
#define DM_ 768
#define NH_ 12

__device__ __forceinline__ unsigned short f2bf(float f) {
  unsigned int u = __float_as_uint(f);
  u += 0x7fffu + ((u >> 16) & 1u);
  return (unsigned short)(u >> 16);
}

__device__ __forceinline__ void load_lds16(const unsigned short* g, unsigned short* l) {
  __builtin_amdgcn_global_load_lds((__attribute__((address_space(1))) void*)g,
                                   (__attribute__((address_space(3))) void*)l, 16, 0, 0);
}

// ---------------- prep: x->bf16 cast + Wqkv/Wo transpose+cast ----------------
__device__ __forceinline__ void transpose_body(const float* __restrict__ src,
                                               unsigned short* __restrict__ dst,
                                               int R, int C, int bx, int by,
                                               float (*t)[65]) {
  int c0 = bx << 6, r0 = by << 6;
  int tid = threadIdx.x;
#pragma unroll
  for (int i = 0; i < 4; i++) {
    int e = (i * 256 + tid) * 4;
    int r = e >> 6, c = e & 63;
    float4 v = *(const float4*)(src + (size_t)(r0 + r) * C + c0 + c);
    t[r][c] = v.x; t[r][c + 1] = v.y; t[r][c + 2] = v.z; t[r][c + 3] = v.w;
  }
  __syncthreads();
#pragma unroll
  for (int i = 0; i < 4; i++) {
    int e = (i * 256 + tid) * 4;
    int r = e >> 6, c = e & 63;
    unsigned short o4[4];
#pragma unroll
    for (int j = 0; j < 4; j++) o4[j] = f2bf(t[c + j][r]);
    *(uint2*)(dst + (size_t)(c0 + r) * R + r0 + c) = *(const uint2*)o4;
  }
}

__global__ __launch_bounds__(256) void prep(const float* __restrict__ x,
                                            const float* __restrict__ Wqkv,
                                            const float* __restrict__ Wo,
                                            unsigned short* __restrict__ xb,
                                            unsigned short* __restrict__ wqkvt,
                                            unsigned short* __restrict__ wot) {
  __shared__ float t[64][65];
  int blk = blockIdx.x;
  if (blk < 3072) {
    int i = (blk * 256 + threadIdx.x) * 4;
    float4 v = *(const float4*)(x + i);
    unsigned short o[4] = {f2bf(v.x), f2bf(v.y), f2bf(v.z), f2bf(v.w)};
    *(uint2*)(xb + i) = *(const uint2*)o;
  } else if (blk < 3072 + 432) {
    int idx = blk - 3072;
    transpose_body(Wqkv, wqkvt, DM_, 3 * DM_, idx % 36, idx / 36, t);
  } else {
    int idx = blk - 3504;
    transpose_body(Wo, wot, DM_, DM_, idx % 12, idx / 12, t);
  }
}

// ---------------- GEMM1: 128x96 tiles, 768 blocks (perfect 3/CU fill) ----------------
// BK=64 XOR-swizzled LDS (chunk g of row r at slot g^(r&7)).
__global__ __launch_bounds__(256, 3) void gemm_qkv(const unsigned short* __restrict__ A,
                                                   const unsigned short* __restrict__ Bt,
                                                   unsigned short* __restrict__ Qb,
                                                   unsigned short* __restrict__ Kb,
                                                   unsigned short* __restrict__ Vtb) {
  const int K = 768;
  __shared__ unsigned short smem[128 * 64 + 96 * 64];
  unsigned short* As = smem;
  unsigned short* Bs = smem + 128 * 64;
  f32x4 acc[4][3];
  f32x4 z = {0.f, 0.f, 0.f, 0.f};
#pragma unroll
  for (int i = 0; i < 4; i++)
#pragma unroll
    for (int j = 0; j < 3; j++) acc[i][j] = z;
  int m0 = blockIdx.x << 7, n0 = blockIdx.y * 96;
  int tid = threadIdx.x, wv = tid >> 6, ln = tid & 63, quad = ln >> 4, lrow = ln & 15;
  int row = tid >> 3;
  int col8 = (tid & 7) ^ (row & 7);
  const unsigned short* a0 = A + (size_t)(m0 + row) * K + col8 * 8;
  const unsigned short* b0 = Bt + (size_t)(n0 + row) * K + col8 * 8;
  int mw = (wv >> 1) << 6, nw = (wv & 1) * 48;
  int sw = lrow & 7;
  for (int kt = 0; kt < K; kt += 64) {
#pragma unroll
    for (int st = 0; st < 4; st++)
      load_lds16(a0 + (size_t)(st * 32) * K + kt, As + (st * 256 + tid) * 8);
#pragma unroll
    for (int st = 0; st < 3; st++)
      load_lds16(b0 + (size_t)(st * 32) * K + kt, Bs + (st * 256 + tid) * 8);
    __syncthreads();
#pragma unroll
    for (int ks = 0; ks < 2; ks++) {
      bf16x8 af[4], bfr[3];
#pragma unroll
      for (int i = 0; i < 4; i++)
        af[i] = *(const bf16x8*)(As + (mw + i * 16 + lrow) * 64 + (((ks * 4 + quad) ^ sw) << 3));
#pragma unroll
      for (int j = 0; j < 3; j++)
        bfr[j] = *(const bf16x8*)(Bs + (nw + j * 16 + lrow) * 64 + (((ks * 4 + quad) ^ sw) << 3));
#pragma unroll
      for (int i = 0; i < 4; i++)
#pragma unroll
        for (int j = 0; j < 3; j++)
          acc[i][j] = __builtin_amdgcn_mfma_f32_16x16x32_bf16(af[i], bfr[j], acc[i][j], 0, 0, 0);
    }
    __syncthreads();
  }
  int mw_l = mw, nw_l = nw;
  int bb = m0 >> 11;
  int which = n0 / DM_;  // 8 tiles each: 0=Q 1=K 2=V (block-uniform)
  int nrem0 = n0 - which * DM_;
  if (which < 2) {
    unsigned short* dstp = which == 0 ? Qb : Kb;
#pragma unroll
    for (int j = 0; j < 3; j++) {
      int nb = nrem0 + nw_l + j * 16;
      int h = nb >> 6, hdb = (nb & 63) + lrow;
      size_t hoff = (size_t)(bb * NH_ + h) << 11;
#pragma unroll
      for (int i = 0; i < 4; i++)
#pragma unroll
        for (int r = 0; r < 4; r++) {
          int s = (m0 + mw_l + i * 16 + quad * 4 + r) & (SEQ_ - 1);
          dstp[((hoff + s) << 6) + hdb] = f2bf(acc[i][j][r]);
        }
    }
  } else {
    // V: 3 slices of (128 s x 32 hd) through LDS, write Vt[bh][hd][s] coalesced.
    const int LSTR = 136;
    int hdl2 = ((wv & 1) << 4) + lrow;
    int hds = tid >> 3, s0 = (tid & 7) << 4;
    int hd_in_block = (hds & 16) * 3 + (hds & 15);  // hds>=16 -> 48 + (hds&15)
#pragma unroll
    for (int j = 0; j < 3; j++) {
      __syncthreads();
#pragma unroll
      for (int i = 0; i < 4; i++)
#pragma unroll
        for (int r = 0; r < 4; r++) {
          int sl = mw_l + i * 16 + quad * 4 + r;
          smem[hdl2 * LSTR + sl] = f2bf(acc[i][j][r]);
        }
      __syncthreads();
      int nb = nrem0 + hd_in_block + j * 16;  // 0..767
      int h = nb >> 6, hdh = nb & 63;
      uint4 p0 = *(const uint4*)&smem[hds * LSTR + s0];
      uint4 p1 = *(const uint4*)&smem[hds * LSTR + s0 + 8];
      size_t vbase = (size_t)(((bb * NH_ + h) << 6) + hdh) * SEQ_ + (m0 & (SEQ_ - 1)) + s0;
      *(uint4*)(Vtb + vbase) = p0;
      *(uint4*)(Vtb + vbase + 8) = p1;
    }
  }
}

// ---------------- GEMM2: out(fp32) = attn_bf @ Wo_t^T, 64x96 tiles, 512 blocks (2/CU) ----------------
__global__ __launch_bounds__(256, 3) void gemm_out(const unsigned short* __restrict__ A,
                                                   const unsigned short* __restrict__ Bt,
                                                   float* __restrict__ out) {
  const int K = 768;
  __shared__ __align__(16) unsigned char sraw[64 * 100 * 4];  // mainloop 20480B; epilogue 25600B
  unsigned short* As = (unsigned short*)sraw;
  unsigned short* Bs = As + 64 * 64;
  f32x4 acc[2][3];
  f32x4 z = {0.f, 0.f, 0.f, 0.f};
#pragma unroll
  for (int i = 0; i < 2; i++)
#pragma unroll
    for (int j = 0; j < 3; j++) acc[i][j] = z;
  int m0 = blockIdx.x << 6, n0 = blockIdx.y * 96;
  int tid = threadIdx.x, wv = tid >> 6, ln = tid & 63, quad = ln >> 4, lrow = ln & 15;
  int row = tid >> 3;
  int col8 = (tid & 7) ^ (row & 7);
  const unsigned short* a0 = A + (size_t)(m0 + row) * K + col8 * 8;
  const unsigned short* b0 = Bt + (size_t)(n0 + row) * K + col8 * 8;
  int mw = (wv >> 1) << 5, nw = (wv & 1) * 48;
  int sw = lrow & 7;
  for (int kt = 0; kt < K; kt += 64) {
#pragma unroll
    for (int st = 0; st < 2; st++)
      load_lds16(a0 + (size_t)(st * 32) * K + kt, As + (st * 256 + tid) * 8);
#pragma unroll
    for (int st = 0; st < 3; st++)
      load_lds16(b0 + (size_t)(st * 32) * K + kt, Bs + (st * 256 + tid) * 8);
    __syncthreads();
#pragma unroll
    for (int ks = 0; ks < 2; ks++) {
      bf16x8 af[2], bfr[3];
#pragma unroll
      for (int i = 0; i < 2; i++)
        af[i] = *(const bf16x8*)(As + (mw + i * 16 + lrow) * 64 + (((ks * 4 + quad) ^ sw) << 3));
#pragma unroll
      for (int j = 0; j < 3; j++)
        bfr[j] = *(const bf16x8*)(Bs + (nw + j * 16 + lrow) * 64 + (((ks * 4 + quad) ^ sw) << 3));
#pragma unroll
      for (int i = 0; i < 2; i++)
#pragma unroll
        for (int j = 0; j < 3; j++)
          acc[i][j] = __builtin_amdgcn_mfma_f32_16x16x32_bf16(af[i], bfr[j], acc[i][j], 0, 0, 0);
    }
    __syncthreads();
  }
  // LDS-coalesced fp32 epilogue: stride 100 floats (100%32=4 -> no 4-quad bank alias)
  float* fs = (float*)sraw;
  __syncthreads();
#pragma unroll
  for (int i = 0; i < 2; i++)
#pragma unroll
    for (int j = 0; j < 3; j++)
#pragma unroll
      for (int r = 0; r < 4; r++)
        fs[(mw + i * 16 + quad * 4 + r) * 100 + nw + j * 16 + lrow] = acc[i][j][r];
  __syncthreads();
  // copy out: 64 rows x 96 floats as float4 (24 per row), 1536 float4 over 6 rounds
#pragma unroll
  for (int rd = 0; rd < 6; rd++) {
    int idx = rd * 256 + tid;
    int r_ = idx / 24, c4 = idx % 24;
    float4 v = *(const float4*)&fs[r_ * 100 + c4 * 4];
    *(float4*)(out + (size_t)(m0 + r_) * DM_ + n0 + c4 * 4) = v;
  }
}

// ---------------- windowed attention ----------------
// Window-mask algebra: d = qg-kg = 64 + (quad*4+r) - (t*16+lrow).
// For t in [1,7] every in-bounds key is in-window; OOB keys die via the validity
// check in mneg. Only t=0 (mask iff lrow<qr) and t=8 (mask iff lrow>qr) need a mask.
__global__ __launch_bounds__(256, 3) void attn_kernel(const unsigned short* __restrict__ Qb,
                                                      const unsigned short* __restrict__ Kb,
                                                      const unsigned short* __restrict__ Vtb,
                                                      const float* __restrict__ pmask,
                                                      unsigned short* __restrict__ Obf) {
  __shared__ unsigned short Ps[4][16 * 168];  // per-wave P, padded stride 168
  int blk = blockIdx.x;
  int tile = blk & 31, bh = blk >> 5;
  int b = bh / NH_, h = bh % NH_;
  int q0 = tile << 6;
  int kstart = q0 - 64;
  int tid = threadIdx.x, wv = tid >> 6, ln = tid & 63, quad = ln >> 4, lrow = ln & 15;
  int kb = wv << 4;
  int qw = q0 + (wv << 4);

  const unsigned short* Qg = Qb + ((size_t)bh << 11) * 64;
  const unsigned short* Kg = Kb + ((size_t)bh << 11) * 64;
  const unsigned short* Vg = Vtb + ((size_t)bh << 6) * SEQ_;

  bf16x8 qf0 = *(const bf16x8*)(Qg + (qw + lrow) * 64 + quad * 8);
  bf16x8 qf1 = *(const bf16x8*)(Qg + (qw + lrow) * 64 + 32 + quad * 8);

  float sc[9][4];
#pragma unroll
  for (int t = 0; t < 9; t++) {
    int kg = kstart + kb + t * 16 + lrow;
    int kgc = kg < 0 ? 0 : (kg > SEQ_ - 1 ? SEQ_ - 1 : kg);
    bf16x8 kf0 = *(const bf16x8*)(Kg + (size_t)kgc * 64 + quad * 8);
    bf16x8 kf1 = *(const bf16x8*)(Kg + (size_t)kgc * 64 + 32 + quad * 8);
    f32x4 c = {0.f, 0.f, 0.f, 0.f};
    c = __builtin_amdgcn_mfma_f32_16x16x32_bf16(qf0, kf0, c, 0, 0, 0);
    c = __builtin_amdgcn_mfma_f32_16x16x32_bf16(qf1, kf1, c, 0, 0, 0);
    float pv = pmask[(b << 11) + kgc];
    bool valid = (kg >= 0) & (kg < SEQ_);
    float mneg = (valid && pv != 0.0f) ? 0.0f : -1e30f;
#pragma unroll
    for (int r = 0; r < 4; r++) {
      int qr = quad * 4 + r;
      float w = mneg;
      if (t == 0) w = (lrow >= qr) ? w : -1e30f;
      if (t == 8) w = (lrow <= qr) ? w : -1e30f;
      sc[t][r] = c[r] * 0.125f + w;
    }
  }
  float inv[4];
#pragma unroll
  for (int r = 0; r < 4; r++) {
    float mx = sc[0][r];
#pragma unroll
    for (int t = 1; t < 9; t++) mx = fmaxf(mx, sc[t][r]);
    mx = fmaxf(mx, __shfl_xor(mx, 1));
    mx = fmaxf(mx, __shfl_xor(mx, 2));
    mx = fmaxf(mx, __shfl_xor(mx, 4));
    mx = fmaxf(mx, __shfl_xor(mx, 8));
    float s = 0.f;
#pragma unroll
    for (int t = 0; t < 9; t++) {
      sc[t][r] = __expf(sc[t][r] - mx);
      s += sc[t][r];
    }
    s += __shfl_xor(s, 1);
    s += __shfl_xor(s, 2);
    s += __shfl_xor(s, 4);
    s += __shfl_xor(s, 8);
    inv[r] = 1.0f / s;
  }
  unsigned short* Pw = &Ps[wv][0];
#pragma unroll
  for (int t = 0; t < 9; t++)
#pragma unroll
    for (int r = 0; r < 4; r++)
      Pw[(quad * 4 + r) * 168 + t * 16 + lrow] = f2bf(sc[t][r] * inv[r]);
  {
    int prow = ln >> 2, c0 = 144 + (ln & 3) * 4;
    uint2 zz; zz.x = 0; zz.y = 0;
    *(uint2*)(Pw + prow * 168 + c0) = zz;
  }
  __syncthreads();
  f32x4 o[4];
  f32x4 z = {0.f, 0.f, 0.f, 0.f};
#pragma unroll
  for (int tt = 0; tt < 4; tt++) o[tt] = z;
#pragma unroll
  for (int ks = 0; ks < 5; ks++) {
    bf16x8 pf = *(const bf16x8*)(Pw + lrow * 168 + ks * 32 + quad * 8);
    int kg = kstart + kb + ks * 32 + quad * 8;
    int kgc = kg < 0 ? 0 : (kg > SEQ_ - 8 ? SEQ_ - 8 : kg);
#pragma unroll
    for (int tt = 0; tt < 4; tt++) {
      bf16x8 vf = *(const bf16x8*)(Vg + (size_t)(tt * 16 + lrow) * SEQ_ + kgc);
      o[tt] = __builtin_amdgcn_mfma_f32_16x16x32_bf16(pf, vf, o[tt], 0, 0, 0);
    }
  }
#pragma unroll
  for (int tt = 0; tt < 4; tt++)
#pragma unroll
    for (int r = 0; r < 4; r++) {
      int s_ = qw + quad * 4 + r;
      Obf[((size_t)(b << 11) + s_) * DM_ + h * 64 + tt * 16 + lrow] = f2bf(o[tt][r]);
    }
}

extern "C" void kernel_launch(void* const* d_in, const int* in_sizes, int n_in,
                              void* d_out, int out_size, void* d_ws, size_t ws_size,
                              hipStream_t stream) {
  const float* x = (const float*)d_in[0];
  const float* pmask = (const float*)d_in[1];
  const float* Wqkv = (const float*)d_in[2];
  const float* Wo = (const float*)d_in[3];
  float* out = (float*)d_out;
  char* ws = (char*)d_ws;

  unsigned short* xb    = (unsigned short*)(ws + 0);         // 4096*768*2
  unsigned short* wqkvt = (unsigned short*)(ws + 6291456);   // 2304*768*2
  unsigned short* wot   = (unsigned short*)(ws + 9830400);   // 768*768*2
  unsigned short* Qb    = (unsigned short*)(ws + 11010048);  // 24*2048*64*2
  unsigned short* Kb    = (unsigned short*)(ws + 17301504);
  unsigned short* Vtb   = (unsigned short*)(ws + 23592960);  // end 29884416
  unsigned short* attn_bf = xb;  // xb dead after gemm_qkv; reuse

  prep<<<3648, 256, 0, stream>>>(x, Wqkv, Wo, xb, wqkvt, wot);
  gemm_qkv<<<dim3(32, 24), 256, 0, stream>>>(xb, wqkvt, Qb, Kb, Vtb);
  attn_kernel<<<768, 256, 0, stream>>>(Qb, Kb, Vtb, pmask, attn_bf);
  gemm_out<<<dim3(64, 8), 256, 0, stream>>>(attn_bf, wot, out);
}